// Round 5
// baseline (548.961 us; speedup 1.0000x reference)
//
#include <hip/hip_runtime.h>

typedef float f32x4 __attribute__((ext_vector_type(4)));

// Geometry: L = 16384 tokens, Lc = 8192 chunks, H = 4096 hidden
// EMA recurrence y_i = A_i*y_{i-1} + Pc_i*concept_i  (A_i scalar, shared over H)
//
// Single-pass decoupled look-back scan:
//   setup:  decode mask -> start[], A[], Pc[]; zero flags/ticket
//   fused:  per (segment=16 chunks, channel-group=1024ch) block:
//           read concept once -> regs, publish aggregate, look-back for carry,
//           publish inclusive prefix, rescan from regs, write token rows.

#define SEG 16
#define TPB 256
#define SETUP_T 1024

// ---------------- setup ----------------
__global__ void __launch_bounds__(SETUP_T)
setup_kernel(const unsigned char* __restrict__ mask,
             const float* __restrict__ probs,
             float* __restrict__ A, float* __restrict__ Pc,
             int* __restrict__ start,
             int* __restrict__ flags, int nflags,
             int L, int Lc) {
    __shared__ int flag;
    __shared__ int wsum[SETUP_T / 64];
    const int t = threadIdx.x;
    const int lane = t & 63, wv = t >> 6;

    // zero look-back flags + ticket (index nflags)
    for (int i = t; i < nflags + 1; i += SETUP_T) flags[i] = 0;

    if (t == 0) flag = 0;
    __syncthreads();

    // 16 tokens per thread (L == 16384)
    int4 v8 = ((const int4*)mask)[t];   // 16 bytes, u8 view
    // encoding detect: int32 0/1 data has all bytes at pos%4!=0 zero
    int f = (v8.x & (int)0xFFFFFF00) | (v8.y & (int)0xFFFFFF00) |
            (v8.z & (int)0xFFFFFF00) | (v8.w & (int)0xFFFFFF00);
    if (f) atomicOr(&flag, 1);
    __syncthreads();
    const bool isU8 = (flag != 0);

    unsigned mbits = 0;
    if (isU8) {
        unsigned dw[4] = {(unsigned)v8.x, (unsigned)v8.y, (unsigned)v8.z, (unsigned)v8.w};
#pragma unroll
        for (int q = 0; q < 4; ++q)
#pragma unroll
            for (int b = 0; b < 4; ++b)
                if ((dw[q] >> (8 * b)) & 0xFFu) mbits |= 1u << (q * 4 + b);
    } else {
        const int4* m4 = (const int4*)mask;   // i32 view
#pragma unroll
        for (int q = 0; q < 4; ++q) {
            int4 w = m4[t * 4 + q];
            if (w.x) mbits |= 1u << (q * 4 + 0);
            if (w.y) mbits |= 1u << (q * 4 + 1);
            if (w.z) mbits |= 1u << (q * 4 + 2);
            if (w.w) mbits |= 1u << (q * 4 + 3);
        }
    }
    int c = __popc(mbits);

    int s = c;
#pragma unroll
    for (int off = 1; off < 64; off <<= 1) {
        int v = __shfl_up(s, off, 64);
        if (lane >= off) s += v;
    }
    if (lane == 63) wsum[wv] = s;
    __syncthreads();
    if (t == 0) {
        int acc = 0;
        for (int w = 0; w < SETUP_T / 64; ++w) { int x = wsum[w]; wsum[w] = acc; acc += x; }
    }
    __syncthreads();

    int rank = wsum[wv] + (s - c);          // exclusive prefix
    const int t0 = t * 16;
#pragma unroll
    for (int k = 0; k < 16; ++k) {
        if ((mbits >> k) & 1u) {
            if (rank < Lc) {
                int tok = t0 + k;
                start[rank] = tok;
                float p = probs[tok];
                A[rank]  = (rank == 0) ? 0.0f : (1.0f - p);
                Pc[rank] = (rank == 0) ? 1.0f : p;
            }
            rank++;
        }
    }
    if (t == 0) start[Lc] = L;
}

// ---------------- fused single-pass scan (decoupled look-back) ----------------
__global__ void __launch_bounds__(TPB)
fused_scan_kernel(const float* __restrict__ cpt,
                  const float* __restrict__ A, const float* __restrict__ Pc,
                  const int* __restrict__ start,
                  float* __restrict__ Agg, float* __restrict__ Pref,
                  float* __restrict__ Aprod, int* __restrict__ flags,
                  float* __restrict__ out, int H, int CG) {
    __shared__ int sh_blk;
    __shared__ int sh_st;
    __shared__ float sA[SEG], sP[SEG];
    __shared__ int   sS[SEG + 1];

    int* ticket = flags - 1;   // host passes flags+1; ticket at flags[-1] == ws flags[nflags]... (see launch)
    if (threadIdx.x == 0) sh_blk = atomicAdd(ticket, 1);
    __syncthreads();
    const int blk = sh_blk;            // cell id; pred cell = blk - CG
    const int seg = blk / CG;
    const int cg  = blk % CG;
    const int ch  = cg * (TPB * 4) + threadIdx.x * 4;
    const int i0  = seg * SEG;
    const int pay = blk * (TPB * 4) + threadIdx.x * 4;   // payload offset

    if (threadIdx.x < SEG)     { sA[threadIdx.x] = A[i0 + threadIdx.x]; sP[threadIdx.x] = Pc[i0 + threadIdx.x]; }
    if (threadIdx.x < SEG + 1) { sS[threadIdx.x] = start[i0 + threadIdx.x]; }
    __syncthreads();

    // ---- read concept once, build pc[] in regs, aggregate ----
    const int strideF4 = H / 4;
    const f32x4* cp = (const f32x4*)(cpt + (size_t)i0 * H + ch);
    f32x4 pc[SEG];
    f32x4 B = {0.f, 0.f, 0.f, 0.f};
    float aprod = 1.0f;
#pragma unroll
    for (int k = 0; k < SEG; ++k) {
        f32x4 c = cp[(size_t)k * strideF4];
        const float a = sA[k], p = sP[k];
        pc[k] = p * c;
        B = a * B + pc[k];
        aprod *= a;
    }

    // ---- publish ----
    if (seg == 0) {
        *(f32x4*)(Pref + pay) = B;
        __syncthreads();
        if (threadIdx.x == 0)
            __hip_atomic_store(flags + blk, 2, __ATOMIC_RELEASE, __HIP_MEMORY_SCOPE_AGENT);
    } else {
        *(f32x4*)(Agg + pay) = B;
        if (threadIdx.x == 0) Aprod[blk] = aprod;
        __syncthreads();
        if (threadIdx.x == 0)
            __hip_atomic_store(flags + blk, 1, __ATOMIC_RELEASE, __HIP_MEMORY_SCOPE_AGENT);
    }

    // ---- look-back for exclusive carry ----
    f32x4 carry = {0.f, 0.f, 0.f, 0.f};
    if (seg > 0) {
        float coef = 1.0f;
        int j = blk - CG;
        for (;;) {
            if (threadIdx.x == 0) {
                int st;
                do {
                    st = __hip_atomic_load(flags + j, __ATOMIC_ACQUIRE, __HIP_MEMORY_SCOPE_AGENT);
                } while (st == 0);
                sh_st = st;
            }
            __syncthreads();
            const int st = sh_st;
            __syncthreads();
            if (st == 2) {
                f32x4 v = *(const f32x4*)(Pref + (size_t)j * (TPB * 4) + threadIdx.x * 4);
                carry += coef * v;
                break;
            } else {
                f32x4 v = *(const f32x4*)(Agg + (size_t)j * (TPB * 4) + threadIdx.x * 4);
                carry += coef * v;
                coef *= Aprod[j];
                j -= CG;
            }
        }
        // publish inclusive prefix
        f32x4 P = B + aprod * carry;
        *(f32x4*)(Pref + pay) = P;
        __syncthreads();
        if (threadIdx.x == 0)
            __hip_atomic_store(flags + blk, 2, __ATOMIC_RELEASE, __HIP_MEMORY_SCOPE_AGENT);
    }

    // ---- rescan from carry (registers only) + token writes ----
    f32x4 y = carry;
#pragma unroll
    for (int k = 0; k < SEG; ++k) {
        y = sA[k] * y + pc[k];
        const int ts = sS[k], te = sS[k + 1];
        for (int t = ts; t < te; ++t) {
            *(f32x4*)(out + (size_t)t * H + ch) = y;
        }
    }
}

extern "C" void kernel_launch(void* const* d_in, const int* in_sizes, int n_in,
                              void* d_out, int out_size, void* d_ws, size_t ws_size,
                              hipStream_t stream) {
    const float* cpt   = (const float*)d_in[0];                 // [1, Lc, H] f32
    const float* probs = (const float*)d_in[1];                 // [1, L, 1] f32
    const unsigned char* mask = (const unsigned char*)d_in[2];  // [1, L] bool/int

    const int L  = in_sizes[1];           // 16384
    const int H  = out_size / L;          // 4096
    const int Lc = in_sizes[0] / H;       // 8192
    const int G  = Lc / SEG;              // 512
    const int CG = H / (TPB * 4);         // 4
    const int nflags = G * CG;            // 2048

    char* ws = (char*)d_ws;
    size_t off = 0;
    auto alloc = [&](size_t bytes) {
        size_t o = off;
        off += (bytes + 255) & ~(size_t)255;
        return (void*)(ws + o);
    };
    float* A     = (float*)alloc((size_t)Lc * 4);
    float* Pc    = (float*)alloc((size_t)Lc * 4);
    int*   start = (int*)  alloc((size_t)(Lc + 1) * 4);
    float* Aprod = (float*)alloc((size_t)nflags * 4);
    int*   tkt   = (int*)  alloc(256);                      // ticket (own cacheline)
    int*   flags = (int*)  alloc((size_t)(nflags) * 4);
    float* Agg   = (float*)alloc((size_t)nflags * TPB * 4 * 4);   // 8 MiB
    float* Pref  = (float*)alloc((size_t)nflags * TPB * 4 * 4);   // 8 MiB
    (void)ws_size;

    // setup zeroes flags[0..nflags-1] and ticket. Pass flags so that
    // flags[-1] is the ticket: allocate contiguous [ticket][flags...]
    // (tkt was allocated immediately before flags; flags-1 lands in tkt's
    //  256-byte slot, specifically at flags[-1] == last int of tkt block)
    // Zero both via setup: hand it tkt as base with nflags+... simpler: zero
    // tkt and flags separately in setup by passing flags base = tkt area.
    int* zero_base = tkt;   // contiguous: tkt block (64 ints) + flags block
    int  zero_cnt  = 64 + nflags;   // zero everything from tkt to end of flags

    hipLaunchKernelGGL(setup_kernel, dim3(1), dim3(SETUP_T), 0, stream,
                       mask, probs, A, Pc, start, zero_base, zero_cnt - 1, L, Lc);

    // fused kernel: ticket pointer = flags - 1 (last int of tkt block)
    hipLaunchKernelGGL(fused_scan_kernel, dim3(G * CG), dim3(TPB), 0, stream,
                       cpt, A, Pc, start, Agg, Pref, Aprod, flags,
                       (float*)d_out, H, CG);
}

// Round 6
// 116.721 us; speedup vs baseline: 4.7032x; 4.7032x over previous
//
#include <hip/hip_runtime.h>

typedef float f32x4 __attribute__((ext_vector_type(4)));

// Geometry: L = 16384 tokens, Lc = 8192 chunks, H = 4096 hidden
// EMA recurrence y_i = A_i*y_{i-1} + Pc_i*concept_i  (A_i scalar, shared over H)
//
// Pipeline (6 kernels):
//   setup:   decode mask -> start[], A[], Pc[]                      (1 block)
//   segsum:  per-segment (SEG=16) scan -> Bend[G][H], Aseg[G]       (grid 2048)
//   carry1:  supersegment (16 segs) summaries -> Bend2, Aseg2       (grid 128)
//   carry2:  32-step chain -> carry2[G2][H]                         (grid 16)
//   carry3:  expand -> carry_seg[G][H] (exclusive carry per segment)(grid 128)
//   scan_write: load carry row, rescan segment, NT-write token rows (grid 2048)

#define SEG 16
#define TPB 256
#define SETUP_T 1024
#define SSEG 16
#define MAXG2 64

// ---------------- setup ----------------
__global__ void __launch_bounds__(SETUP_T)
setup_kernel(const unsigned char* __restrict__ mask,
             const float* __restrict__ probs,
             float* __restrict__ A, float* __restrict__ Pc,
             int* __restrict__ start, int L, int Lc) {
    __shared__ int flag;
    __shared__ int wsum[SETUP_T / 64];
    const int t = threadIdx.x;
    const int lane = t & 63, wv = t >> 6;
    if (t == 0) flag = 0;
    __syncthreads();

    // 16 tokens per thread (L == 16384)
    int4 v8 = ((const int4*)mask)[t];   // 16 bytes, u8 view
    // encoding detect: int32 0/1 data has all bytes at pos%4!=0 zero
    int f = (v8.x & (int)0xFFFFFF00) | (v8.y & (int)0xFFFFFF00) |
            (v8.z & (int)0xFFFFFF00) | (v8.w & (int)0xFFFFFF00);
    if (f) atomicOr(&flag, 1);
    __syncthreads();
    const bool isU8 = (flag != 0);

    unsigned mbits = 0;
    if (isU8) {
        unsigned dw[4] = {(unsigned)v8.x, (unsigned)v8.y, (unsigned)v8.z, (unsigned)v8.w};
#pragma unroll
        for (int q = 0; q < 4; ++q)
#pragma unroll
            for (int b = 0; b < 4; ++b)
                if ((dw[q] >> (8 * b)) & 0xFFu) mbits |= 1u << (q * 4 + b);
    } else {
        const int4* m4 = (const int4*)mask;   // i32 view
#pragma unroll
        for (int q = 0; q < 4; ++q) {
            int4 w = m4[t * 4 + q];
            if (w.x) mbits |= 1u << (q * 4 + 0);
            if (w.y) mbits |= 1u << (q * 4 + 1);
            if (w.z) mbits |= 1u << (q * 4 + 2);
            if (w.w) mbits |= 1u << (q * 4 + 3);
        }
    }
    int c = __popc(mbits);

    int s = c;
#pragma unroll
    for (int off = 1; off < 64; off <<= 1) {
        int v = __shfl_up(s, off, 64);
        if (lane >= off) s += v;
    }
    if (lane == 63) wsum[wv] = s;
    __syncthreads();
    if (t == 0) {
        int acc = 0;
        for (int w = 0; w < SETUP_T / 64; ++w) { int x = wsum[w]; wsum[w] = acc; acc += x; }
    }
    __syncthreads();

    int rank = wsum[wv] + (s - c);          // exclusive prefix
    const int t0 = t * 16;
#pragma unroll
    for (int k = 0; k < 16; ++k) {
        if ((mbits >> k) & 1u) {
            if (rank < Lc) {
                int tok = t0 + k;
                start[rank] = tok;
                float p = probs[tok];
                A[rank]  = (rank == 0) ? 0.0f : (1.0f - p);
                Pc[rank] = (rank == 0) ? 1.0f : p;
            }
            rank++;
        }
    }
    if (t == 0) start[Lc] = L;
}

// ---------------- pass A: per-segment summaries ----------------
__global__ void __launch_bounds__(TPB)
segsum_kernel(const float* __restrict__ cpt,
              const float* __restrict__ A, const float* __restrict__ Pc,
              float* __restrict__ Bend, float* __restrict__ Aseg,
              int H, int CG) {
    const int g  = blockIdx.x / CG;
    const int cg = blockIdx.x % CG;
    const int ch = cg * (TPB * 4) + threadIdx.x * 4;
    const int i0 = g * SEG;

    __shared__ float sA[SEG], sP[SEG];
    if (threadIdx.x < SEG) { sA[threadIdx.x] = A[i0 + threadIdx.x]; sP[threadIdx.x] = Pc[i0 + threadIdx.x]; }
    __syncthreads();

    const int strideF4 = H / 4;
    const f32x4* cp = (const f32x4*)(cpt + (size_t)i0 * H + ch);
    f32x4 y = {0.f, 0.f, 0.f, 0.f};
    float pa = 1.0f;
#pragma unroll 8
    for (int k = 0; k < SEG; ++k) {
        const float a = sA[k], p = sP[k];
        f32x4 c = cp[(size_t)k * strideF4];
        y = a * y + p * c;
        pa *= a;
    }
    *(f32x4*)(Bend + (size_t)g * H + ch) = y;
    if (threadIdx.x == 0 && cg == 0) Aseg[g] = pa;
}

// ---------------- carry level 1: supersegment summaries ----------------
__global__ void __launch_bounds__(TPB)
carry1_kernel(const float* __restrict__ Bend, const float* __restrict__ Aseg,
              float* __restrict__ Bend2, float* __restrict__ Aseg2,
              int H, int CG) {
    const int g2 = blockIdx.x / CG;
    const int cg = blockIdx.x % CG;
    const int ch = cg * (TPB * 4) + threadIdx.x * 4;
    const int j0 = g2 * SSEG;

    f32x4 b = {0.f, 0.f, 0.f, 0.f};
    float pa = 1.0f;
#pragma unroll 8
    for (int j = 0; j < SSEG; ++j) {
        const float a = Aseg[j0 + j];
        f32x4 bj = *(const f32x4*)(Bend + (size_t)(j0 + j) * H + ch);
        b = bj + a * b;
        pa *= a;
    }
    *(f32x4*)(Bend2 + (size_t)g2 * H + ch) = b;
    if (threadIdx.x == 0 && cg == 0) Aseg2[g2] = pa;
}

// ---------------- carry level 2: chain over supersegments ----------------
__global__ void __launch_bounds__(TPB)
carry2_kernel(const float* __restrict__ Bend2, const float* __restrict__ Aseg2,
              float* __restrict__ carry2, int H, int G2) {
    __shared__ float sA2[MAXG2];
    const int c0 = blockIdx.x * TPB + threadIdx.x;
    if (threadIdx.x < G2) sA2[threadIdx.x] = Aseg2[threadIdx.x];
    __syncthreads();
    float cr = 0.0f;
    carry2[c0] = 0.0f;
#pragma unroll 4
    for (int g2 = 1; g2 < G2; ++g2) {
        float b = Bend2[(size_t)(g2 - 1) * H + c0];
        cr = b + sA2[g2 - 1] * cr;
        carry2[(size_t)g2 * H + c0] = cr;
    }
}

// ---------------- carry level 3: expand to per-segment carries ----------------
__global__ void __launch_bounds__(TPB)
carry3_kernel(const float* __restrict__ Bend, const float* __restrict__ Aseg,
              const float* __restrict__ carry2,
              float* __restrict__ carry_seg, int H, int CG) {
    const int g2 = blockIdx.x / CG;
    const int cg = blockIdx.x % CG;
    const int ch = cg * (TPB * 4) + threadIdx.x * 4;
    const int j0 = g2 * SSEG;

    __shared__ float sAs[SSEG];
    if (threadIdx.x < SSEG) sAs[threadIdx.x] = Aseg[j0 + threadIdx.x];
    __syncthreads();

    f32x4 cr = *(const f32x4*)(carry2 + (size_t)g2 * H + ch);
    *(f32x4*)(carry_seg + (size_t)j0 * H + ch) = cr;
#pragma unroll
    for (int j = 1; j < SSEG; ++j) {
        f32x4 b = *(const f32x4*)(Bend + (size_t)(j0 + j - 1) * H + ch);
        cr = b + sAs[j - 1] * cr;
        *(f32x4*)(carry_seg + (size_t)(j0 + j) * H + ch) = cr;
    }
}

// ---------------- pass C: rescan + NT token writes ----------------
__global__ void __launch_bounds__(TPB)
scan_write_kernel(const float* __restrict__ cpt,
                  const float* __restrict__ A, const float* __restrict__ Pc,
                  const int* __restrict__ start,
                  const float* __restrict__ carry_seg,
                  float* __restrict__ out, int H, int CG) {
    const int g  = blockIdx.x / CG;
    const int cg = blockIdx.x % CG;
    const int ch = cg * (TPB * 4) + threadIdx.x * 4;
    const int i0 = g * SEG;

    // issue carry load first so it overlaps LDS staging
    f32x4 y = *(const f32x4*)(carry_seg + (size_t)g * H + ch);

    __shared__ float sA[SEG], sP[SEG];
    __shared__ int   sS[SEG + 1];
    if (threadIdx.x < SEG)     { sA[threadIdx.x] = A[i0 + threadIdx.x]; sP[threadIdx.x] = Pc[i0 + threadIdx.x]; }
    if (threadIdx.x < SEG + 1) { sS[threadIdx.x] = start[i0 + threadIdx.x]; }
    __syncthreads();

    const int strideF4 = H / 4;
    const f32x4* cp = (const f32x4*)(cpt + (size_t)i0 * H + ch);
#pragma unroll 4
    for (int k = 0; k < SEG; ++k) {
        const float a = sA[k], p = sP[k];
        f32x4 c = cp[(size_t)k * strideF4];
        y = a * y + p * c;
        const int ts = sS[k], te = sS[k + 1];
        for (int t = ts; t < te; ++t) {
            __builtin_nontemporal_store(y, (f32x4*)(out + (size_t)t * H + ch));
        }
    }
}

extern "C" void kernel_launch(void* const* d_in, const int* in_sizes, int n_in,
                              void* d_out, int out_size, void* d_ws, size_t ws_size,
                              hipStream_t stream) {
    const float* cpt   = (const float*)d_in[0];                 // [1, Lc, H] f32
    const float* probs = (const float*)d_in[1];                 // [1, L, 1] f32
    const unsigned char* mask = (const unsigned char*)d_in[2];  // [1, L] bool/int

    const int L  = in_sizes[1];           // 16384
    const int H  = out_size / L;          // 4096
    const int Lc = in_sizes[0] / H;       // 8192
    const int G  = Lc / SEG;              // 512
    const int G2 = G / SSEG;              // 32
    const int CG = H / (TPB * 4);         // 4

    char* ws = (char*)d_ws;
    size_t off = 0;
    auto alloc = [&](size_t bytes) {
        size_t o = off;
        off += (bytes + 255) & ~(size_t)255;
        return (void*)(ws + o);
    };
    float* A        = (float*)alloc((size_t)Lc * 4);
    float* Pc       = (float*)alloc((size_t)Lc * 4);
    int*   start    = (int*)  alloc((size_t)(Lc + 1) * 4);
    float* Aseg     = (float*)alloc((size_t)G * 4);
    float* Aseg2    = (float*)alloc((size_t)G2 * 4);
    float* Bend     = (float*)alloc((size_t)G * H * 4);    // 8 MB
    float* Bend2    = (float*)alloc((size_t)G2 * H * 4);   // 0.5 MB
    float* carry2   = (float*)alloc((size_t)G2 * H * 4);   // 0.5 MB
    float* carryseg = (float*)alloc((size_t)G * H * 4);    // 8 MB
    (void)ws_size;

    hipLaunchKernelGGL(setup_kernel, dim3(1), dim3(SETUP_T), 0, stream,
                       mask, probs, A, Pc, start, L, Lc);
    hipLaunchKernelGGL(segsum_kernel, dim3(G * CG), dim3(TPB), 0, stream,
                       cpt, A, Pc, Bend, Aseg, H, CG);
    hipLaunchKernelGGL(carry1_kernel, dim3(G2 * CG), dim3(TPB), 0, stream,
                       Bend, Aseg, Bend2, Aseg2, H, CG);
    hipLaunchKernelGGL(carry2_kernel, dim3(H / TPB), dim3(TPB), 0, stream,
                       Bend2, Aseg2, carry2, H, G2);
    hipLaunchKernelGGL(carry3_kernel, dim3(G2 * CG), dim3(TPB), 0, stream,
                       Bend, Aseg, carry2, carryseg, H, CG);
    hipLaunchKernelGGL(scan_write_kernel, dim3(G * CG), dim3(TPB), 0, stream,
                       cpt, A, Pc, start, carryseg, (float*)d_out, H, CG);
}

// Round 7
// 112.527 us; speedup vs baseline: 4.8785x; 1.0373x over previous
//
#include <hip/hip_runtime.h>

typedef float f32x4 __attribute__((ext_vector_type(4)));

// Geometry: L = 16384 tokens, Lc = 8192 chunks, H = 4096 hidden
// EMA recurrence y_i = A_i*y_{i-1} + Pc_i*concept_i  (A_i scalar, shared over H)
//
// Pipeline (5 kernels):
//   setup:   decode mask -> start[], A[], Pc[]                      (1 block)
//   segsum:  per-segment (SEG=16) scan -> Bend[G][H], Aseg[G]       (grid 2048)
//   carry1:  supersegment (16 segs) summaries -> Bend2, Aseg2       (grid 128)
//   carry23: weighted-sum over Bend2 rows -> supersegment carry,
//            expand within supersegment -> carry_seg[G][H]          (grid 128)
//   scan_write: carry row + batched concept loads, rescan, NT-write (grid 2048)

#define SEG 16
#define TPB 256
#define SETUP_T 1024
#define SSEG 16
#define MAXG2 64

// ---------------- setup ----------------
__global__ void __launch_bounds__(SETUP_T)
setup_kernel(const unsigned char* __restrict__ mask,
             const float* __restrict__ probs,
             float* __restrict__ A, float* __restrict__ Pc,
             int* __restrict__ start, int L, int Lc) {
    __shared__ int flag;
    __shared__ int wsum[SETUP_T / 64];
    const int t = threadIdx.x;
    const int lane = t & 63, wv = t >> 6;
    if (t == 0) flag = 0;
    __syncthreads();

    // 16 tokens per thread (L == 16384)
    int4 v8 = ((const int4*)mask)[t];   // 16 bytes, u8 view
    // encoding detect: int32 0/1 data has all bytes at pos%4!=0 zero
    int f = (v8.x & (int)0xFFFFFF00) | (v8.y & (int)0xFFFFFF00) |
            (v8.z & (int)0xFFFFFF00) | (v8.w & (int)0xFFFFFF00);
    if (f) atomicOr(&flag, 1);
    __syncthreads();
    const bool isU8 = (flag != 0);

    unsigned mbits = 0;
    if (isU8) {
        unsigned dw[4] = {(unsigned)v8.x, (unsigned)v8.y, (unsigned)v8.z, (unsigned)v8.w};
#pragma unroll
        for (int q = 0; q < 4; ++q)
#pragma unroll
            for (int b = 0; b < 4; ++b)
                if ((dw[q] >> (8 * b)) & 0xFFu) mbits |= 1u << (q * 4 + b);
    } else {
        const int4* m4 = (const int4*)mask;   // i32 view
#pragma unroll
        for (int q = 0; q < 4; ++q) {
            int4 w = m4[t * 4 + q];
            if (w.x) mbits |= 1u << (q * 4 + 0);
            if (w.y) mbits |= 1u << (q * 4 + 1);
            if (w.z) mbits |= 1u << (q * 4 + 2);
            if (w.w) mbits |= 1u << (q * 4 + 3);
        }
    }
    int c = __popc(mbits);

    int s = c;
#pragma unroll
    for (int off = 1; off < 64; off <<= 1) {
        int v = __shfl_up(s, off, 64);
        if (lane >= off) s += v;
    }
    if (lane == 63) wsum[wv] = s;
    __syncthreads();
    if (t == 0) {
        int acc = 0;
        for (int w = 0; w < SETUP_T / 64; ++w) { int x = wsum[w]; wsum[w] = acc; acc += x; }
    }
    __syncthreads();

    int rank = wsum[wv] + (s - c);          // exclusive prefix
    const int t0 = t * 16;
#pragma unroll
    for (int k = 0; k < 16; ++k) {
        if ((mbits >> k) & 1u) {
            if (rank < Lc) {
                int tok = t0 + k;
                start[rank] = tok;
                float p = probs[tok];
                A[rank]  = (rank == 0) ? 0.0f : (1.0f - p);
                Pc[rank] = (rank == 0) ? 1.0f : p;
            }
            rank++;
        }
    }
    if (t == 0) start[Lc] = L;
}

// ---------------- pass A: per-segment summaries ----------------
__global__ void __launch_bounds__(TPB)
segsum_kernel(const float* __restrict__ cpt,
              const float* __restrict__ A, const float* __restrict__ Pc,
              float* __restrict__ Bend, float* __restrict__ Aseg,
              int H, int CG) {
    const int g  = blockIdx.x / CG;
    const int cg = blockIdx.x % CG;
    const int ch = cg * (TPB * 4) + threadIdx.x * 4;
    const int i0 = g * SEG;

    __shared__ float sA[SEG], sP[SEG];
    if (threadIdx.x < SEG) { sA[threadIdx.x] = A[i0 + threadIdx.x]; sP[threadIdx.x] = Pc[i0 + threadIdx.x]; }
    __syncthreads();

    const int strideF4 = H / 4;
    const f32x4* cp = (const f32x4*)(cpt + (size_t)i0 * H + ch);
    f32x4 y = {0.f, 0.f, 0.f, 0.f};
    float pa = 1.0f;
#pragma unroll 8
    for (int k = 0; k < SEG; ++k) {
        const float a = sA[k], p = sP[k];
        f32x4 c = cp[(size_t)k * strideF4];
        y = a * y + p * c;
        pa *= a;
    }
    *(f32x4*)(Bend + (size_t)g * H + ch) = y;
    if (threadIdx.x == 0 && cg == 0) Aseg[g] = pa;
}

// ---------------- carry level 1: supersegment summaries ----------------
__global__ void __launch_bounds__(TPB)
carry1_kernel(const float* __restrict__ Bend, const float* __restrict__ Aseg,
              float* __restrict__ Bend2, float* __restrict__ Aseg2,
              int H, int CG) {
    const int g2 = blockIdx.x / CG;
    const int cg = blockIdx.x % CG;
    const int ch = cg * (TPB * 4) + threadIdx.x * 4;
    const int j0 = g2 * SSEG;

    __shared__ float sAs[SSEG];
    if (threadIdx.x < SSEG) sAs[threadIdx.x] = Aseg[j0 + threadIdx.x];
    __syncthreads();

    f32x4 b = {0.f, 0.f, 0.f, 0.f};
    float pa = 1.0f;
#pragma unroll 8
    for (int j = 0; j < SSEG; ++j) {
        const float a = sAs[j];
        f32x4 bj = *(const f32x4*)(Bend + (size_t)(j0 + j) * H + ch);
        b = bj + a * b;
        pa *= a;
    }
    *(f32x4*)(Bend2 + (size_t)g2 * H + ch) = b;
    if (threadIdx.x == 0 && cg == 0) Aseg2[g2] = pa;
}

// ---------------- carry23: weighted-sum carry + per-segment expansion ----------------
// carry2(g2) = sum_{j<g2} ( prod_{j<k<g2} Aseg2[k] ) * Bend2[j]   (independent loads)
// then expand within supersegment via Bend rows.
__global__ void __launch_bounds__(TPB)
carry23_kernel(const float* __restrict__ Bend, const float* __restrict__ Aseg,
               const float* __restrict__ Bend2, const float* __restrict__ Aseg2,
               float* __restrict__ carry_seg, int H, int CG, int G2) {
    const int g2 = blockIdx.x / CG;
    const int cg = blockIdx.x % CG;
    const int ch = cg * (TPB * 4) + threadIdx.x * 4;
    const int j0 = g2 * SSEG;

    __shared__ float sA2[MAXG2];
    __shared__ float sAs[SSEG];
    if (threadIdx.x < G2)   sA2[threadIdx.x] = Aseg2[threadIdx.x];
    if (threadIdx.x < SSEG) sAs[threadIdx.x] = Aseg[j0 + threadIdx.x];
    __syncthreads();

    // weights: w[j] = prod_{j<k<g2} sA2[k]; computed backwards in registers
    f32x4 cr = {0.f, 0.f, 0.f, 0.f};
    {
        float w = 1.0f;
        for (int j = g2 - 1; j >= 0; --j) {
            f32x4 b2 = *(const f32x4*)(Bend2 + (size_t)j * H + ch);
            cr += w * b2;
            w *= sA2[j];
        }
    }

    // expand within supersegment: carry_seg[j0 + j]
    *(f32x4*)(carry_seg + (size_t)j0 * H + ch) = cr;
#pragma unroll
    for (int j = 1; j < SSEG; ++j) {
        f32x4 b = *(const f32x4*)(Bend + (size_t)(j0 + j - 1) * H + ch);
        cr = b + sAs[j - 1] * cr;
        *(f32x4*)(carry_seg + (size_t)(j0 + j) * H + ch) = cr;
    }
}

// ---------------- pass C: batched loads, rescan, NT token writes ----------------
__global__ void __launch_bounds__(TPB)
scan_write_kernel(const float* __restrict__ cpt,
                  const float* __restrict__ A, const float* __restrict__ Pc,
                  const int* __restrict__ start,
                  const float* __restrict__ carry_seg,
                  float* __restrict__ out, int H, int CG) {
    const int g  = blockIdx.x / CG;
    const int cg = blockIdx.x % CG;
    const int ch = cg * (TPB * 4) + threadIdx.x * 4;
    const int i0 = g * SEG;

    // issue carry load first so it overlaps LDS staging
    f32x4 y = *(const f32x4*)(carry_seg + (size_t)g * H + ch);

    __shared__ float sA[SEG], sP[SEG];
    __shared__ int   sS[SEG + 1];
    if (threadIdx.x < SEG)     { sA[threadIdx.x] = A[i0 + threadIdx.x]; sP[threadIdx.x] = Pc[i0 + threadIdx.x]; }
    if (threadIdx.x < SEG + 1) { sS[threadIdx.x] = start[i0 + threadIdx.x]; }
    __syncthreads();

    // batch all concept loads (independent of the recurrence chain)
    const int strideF4 = H / 4;
    const f32x4* cp = (const f32x4*)(cpt + (size_t)i0 * H + ch);
    f32x4 c[SEG];
#pragma unroll
    for (int k = 0; k < SEG; ++k) c[k] = cp[(size_t)k * strideF4];

#pragma unroll
    for (int k = 0; k < SEG; ++k) {
        y = sA[k] * y + sP[k] * c[k];
        const int ts = sS[k], te = sS[k + 1];
        for (int t = ts; t < te; ++t) {
            __builtin_nontemporal_store(y, (f32x4*)(out + (size_t)t * H + ch));
        }
    }
}

extern "C" void kernel_launch(void* const* d_in, const int* in_sizes, int n_in,
                              void* d_out, int out_size, void* d_ws, size_t ws_size,
                              hipStream_t stream) {
    const float* cpt   = (const float*)d_in[0];                 // [1, Lc, H] f32
    const float* probs = (const float*)d_in[1];                 // [1, L, 1] f32
    const unsigned char* mask = (const unsigned char*)d_in[2];  // [1, L] bool/int

    const int L  = in_sizes[1];           // 16384
    const int H  = out_size / L;          // 4096
    const int Lc = in_sizes[0] / H;       // 8192
    const int G  = Lc / SEG;              // 512
    const int G2 = G / SSEG;              // 32
    const int CG = H / (TPB * 4);         // 4

    char* ws = (char*)d_ws;
    size_t off = 0;
    auto alloc = [&](size_t bytes) {
        size_t o = off;
        off += (bytes + 255) & ~(size_t)255;
        return (void*)(ws + o);
    };
    float* A        = (float*)alloc((size_t)Lc * 4);
    float* Pc       = (float*)alloc((size_t)Lc * 4);
    int*   start    = (int*)  alloc((size_t)(Lc + 1) * 4);
    float* Aseg     = (float*)alloc((size_t)G * 4);
    float* Aseg2    = (float*)alloc((size_t)G2 * 4);
    float* Bend     = (float*)alloc((size_t)G * H * 4);    // 8 MB
    float* Bend2    = (float*)alloc((size_t)G2 * H * 4);   // 0.5 MB
    float* carryseg = (float*)alloc((size_t)G * H * 4);    // 8 MB
    (void)ws_size;

    hipLaunchKernelGGL(setup_kernel, dim3(1), dim3(SETUP_T), 0, stream,
                       mask, probs, A, Pc, start, L, Lc);
    hipLaunchKernelGGL(segsum_kernel, dim3(G * CG), dim3(TPB), 0, stream,
                       cpt, A, Pc, Bend, Aseg, H, CG);
    hipLaunchKernelGGL(carry1_kernel, dim3(G2 * CG), dim3(TPB), 0, stream,
                       Bend, Aseg, Bend2, Aseg2, H, CG);
    hipLaunchKernelGGL(carry23_kernel, dim3(G2 * CG), dim3(TPB), 0, stream,
                       Bend, Aseg, Bend2, Aseg2, carryseg, H, CG, G2);
    hipLaunchKernelGGL(scan_write_kernel, dim3(G * CG), dim3(TPB), 0, stream,
                       cpt, A, Pc, start, carryseg, (float*)d_out, H, CG);
}

// Round 8
// 105.154 us; speedup vs baseline: 5.2205x; 1.0701x over previous
//
#include <hip/hip_runtime.h>

typedef float f32x4 __attribute__((ext_vector_type(4)));

// Geometry: L = 16384 tokens, Lc = 8192 chunks, H = 4096 hidden
// EMA recurrence y_i = A_i*y_{i-1} + Pc_i*concept_i  (A_i scalar, shared over H)
//
// Pipeline (3 kernels):
//   setup:      decode mask -> start[], A[], Pc[]                    (1 block)
//   segsum:     per-segment (SEG=16) scan -> Bend[G][H], Aseg[G]     (grid 2048)
//   scan_write: per-block carry via short decay-truncated walk over
//               Bend spine (w = prod Aseg < 1e-10 after ~2 segs since
//               a in (0,1)), rescan segment, NT-write token rows      (grid 2048)

#define SEG 16
#define TPB 256
#define SETUP_T 1024

// ---------------- setup ----------------
__global__ void __launch_bounds__(SETUP_T)
setup_kernel(const unsigned char* __restrict__ mask,
             const float* __restrict__ probs,
             float* __restrict__ A, float* __restrict__ Pc,
             int* __restrict__ start, int L, int Lc) {
    __shared__ int flag;
    __shared__ int wsum[SETUP_T / 64];
    const int t = threadIdx.x;
    const int lane = t & 63, wv = t >> 6;
    if (t == 0) flag = 0;
    __syncthreads();

    // 16 tokens per thread (L == 16384)
    int4 v8 = ((const int4*)mask)[t];   // 16 bytes, u8 view
    // encoding detect: int32 0/1 data has all bytes at pos%4!=0 zero
    int f = (v8.x & (int)0xFFFFFF00) | (v8.y & (int)0xFFFFFF00) |
            (v8.z & (int)0xFFFFFF00) | (v8.w & (int)0xFFFFFF00);
    if (f) atomicOr(&flag, 1);
    __syncthreads();
    const bool isU8 = (flag != 0);

    unsigned mbits = 0;
    if (isU8) {
        unsigned dw[4] = {(unsigned)v8.x, (unsigned)v8.y, (unsigned)v8.z, (unsigned)v8.w};
#pragma unroll
        for (int q = 0; q < 4; ++q)
#pragma unroll
            for (int b = 0; b < 4; ++b)
                if ((dw[q] >> (8 * b)) & 0xFFu) mbits |= 1u << (q * 4 + b);
    } else {
        const int4* m4 = (const int4*)mask;   // i32 view
#pragma unroll
        for (int q = 0; q < 4; ++q) {
            int4 w = m4[t * 4 + q];
            if (w.x) mbits |= 1u << (q * 4 + 0);
            if (w.y) mbits |= 1u << (q * 4 + 1);
            if (w.z) mbits |= 1u << (q * 4 + 2);
            if (w.w) mbits |= 1u << (q * 4 + 3);
        }
    }
    int c = __popc(mbits);

    int s = c;
#pragma unroll
    for (int off = 1; off < 64; off <<= 1) {
        int v = __shfl_up(s, off, 64);
        if (lane >= off) s += v;
    }
    if (lane == 63) wsum[wv] = s;
    __syncthreads();
    if (t == 0) {
        int acc = 0;
        for (int w = 0; w < SETUP_T / 64; ++w) { int x = wsum[w]; wsum[w] = acc; acc += x; }
    }
    __syncthreads();

    int rank = wsum[wv] + (s - c);          // exclusive prefix
    const int t0 = t * 16;
#pragma unroll
    for (int k = 0; k < 16; ++k) {
        if ((mbits >> k) & 1u) {
            if (rank < Lc) {
                int tok = t0 + k;
                start[rank] = tok;
                float p = probs[tok];
                A[rank]  = (rank == 0) ? 0.0f : (1.0f - p);
                Pc[rank] = (rank == 0) ? 1.0f : p;
            }
            rank++;
        }
    }
    if (t == 0) start[Lc] = L;
}

// ---------------- pass A: per-segment summaries ----------------
__global__ void __launch_bounds__(TPB)
segsum_kernel(const float* __restrict__ cpt,
              const float* __restrict__ A, const float* __restrict__ Pc,
              float* __restrict__ Bend, float* __restrict__ Aseg,
              int H, int CG) {
    const int g  = blockIdx.x / CG;
    const int cg = blockIdx.x % CG;
    const int ch = cg * (TPB * 4) + threadIdx.x * 4;
    const int i0 = g * SEG;

    __shared__ float sA[SEG], sP[SEG];
    if (threadIdx.x < SEG) { sA[threadIdx.x] = A[i0 + threadIdx.x]; sP[threadIdx.x] = Pc[i0 + threadIdx.x]; }
    __syncthreads();

    const int strideF4 = H / 4;
    const f32x4* cp = (const f32x4*)(cpt + (size_t)i0 * H + ch);
    f32x4 y = {0.f, 0.f, 0.f, 0.f};
    float pa = 1.0f;
#pragma unroll 8
    for (int k = 0; k < SEG; ++k) {
        const float a = sA[k], p = sP[k];
        f32x4 c = cp[(size_t)k * strideF4];
        y = a * y + p * c;
        pa *= a;
    }
    *(f32x4*)(Bend + (size_t)g * H + ch) = y;
    if (threadIdx.x == 0 && cg == 0) Aseg[g] = pa;
}

// ---------------- pass C: truncated carry walk + rescan + NT writes ----------------
__global__ void __launch_bounds__(TPB)
scan_write_kernel(const float* __restrict__ cpt,
                  const float* __restrict__ A, const float* __restrict__ Pc,
                  const int* __restrict__ start,
                  const float* __restrict__ Bend, const float* __restrict__ Aseg,
                  float* __restrict__ out, int H, int CG) {
    const int g  = blockIdx.x / CG;
    const int cg = blockIdx.x % CG;
    const int ch = cg * (TPB * 4) + threadIdx.x * 4;
    const int i0 = g * SEG;

    __shared__ float sA[SEG], sP[SEG];
    __shared__ int   sS[SEG + 1];
    if (threadIdx.x < SEG)     { sA[threadIdx.x] = A[i0 + threadIdx.x]; sP[threadIdx.x] = Pc[i0 + threadIdx.x]; }
    if (threadIdx.x < SEG + 1) { sS[threadIdx.x] = start[i0 + threadIdx.x]; }
    __syncthreads();

    // batch all concept loads (independent of everything; long-latency, issue first)
    const int strideF4 = H / 4;
    const f32x4* cp = (const f32x4*)(cpt + (size_t)i0 * H + ch);
    f32x4 c[SEG];
#pragma unroll
    for (int k = 0; k < SEG; ++k) c[k] = cp[(size_t)k * strideF4];

    // exclusive carry: decay-truncated backward walk over Bend spine.
    // carry(g) = sum_{j<g} ( prod_{j<k<g} Aseg[k] ) * Bend[j]
    // weights strictly decrease (a in (0,1)); stop below fp32 noise.
    f32x4 y = {0.f, 0.f, 0.f, 0.f};
    {
        float w = 1.0f;
        for (int j = g - 1; j >= 0; --j) {
            f32x4 b = *(const f32x4*)(Bend + (size_t)j * H + ch);
            y += w * b;
            w *= Aseg[j];
            if (w < 1e-10f) break;
        }
    }

    // rescan from carry + token writes
#pragma unroll
    for (int k = 0; k < SEG; ++k) {
        y = sA[k] * y + sP[k] * c[k];
        const int ts = sS[k], te = sS[k + 1];
        for (int t = ts; t < te; ++t) {
            __builtin_nontemporal_store(y, (f32x4*)(out + (size_t)t * H + ch));
        }
    }
}

extern "C" void kernel_launch(void* const* d_in, const int* in_sizes, int n_in,
                              void* d_out, int out_size, void* d_ws, size_t ws_size,
                              hipStream_t stream) {
    const float* cpt   = (const float*)d_in[0];                 // [1, Lc, H] f32
    const float* probs = (const float*)d_in[1];                 // [1, L, 1] f32
    const unsigned char* mask = (const unsigned char*)d_in[2];  // [1, L] bool/int

    const int L  = in_sizes[1];           // 16384
    const int H  = out_size / L;          // 4096
    const int Lc = in_sizes[0] / H;       // 8192
    const int G  = Lc / SEG;              // 512
    const int CG = H / (TPB * 4);         // 4

    char* ws = (char*)d_ws;
    size_t off = 0;
    auto alloc = [&](size_t bytes) {
        size_t o = off;
        off += (bytes + 255) & ~(size_t)255;
        return (void*)(ws + o);
    };
    float* A     = (float*)alloc((size_t)Lc * 4);
    float* Pc    = (float*)alloc((size_t)Lc * 4);
    int*   start = (int*)  alloc((size_t)(Lc + 1) * 4);
    float* Aseg  = (float*)alloc((size_t)G * 4);
    float* Bend  = (float*)alloc((size_t)G * H * 4);    // 8 MB
    (void)ws_size;

    hipLaunchKernelGGL(setup_kernel, dim3(1), dim3(SETUP_T), 0, stream,
                       mask, probs, A, Pc, start, L, Lc);
    hipLaunchKernelGGL(segsum_kernel, dim3(G * CG), dim3(TPB), 0, stream,
                       cpt, A, Pc, Bend, Aseg, H, CG);
    hipLaunchKernelGGL(scan_write_kernel, dim3(G * CG), dim3(TPB), 0, stream,
                       cpt, A, Pc, start, Bend, Aseg, (float*)d_out, H, CG);
}